// Round 1
// 88.941 us; speedup vs baseline: 1.0406x; 1.0406x over previous
//
#include <hip/hip_runtime.h>
#include <hip/hip_bf16.h>
#include <hip/hip_fp16.h>

// Problem constants (fixed by reference)
#define NB     512
#define INF    1024
#define OUTF   64
#define PROJ   1024          // OUT_FEATURES * KERNEL_DIMS
#define OROW   (INF + OUTF)  // 1088

typedef short short8 __attribute__((ext_vector_type(8)));
typedef float floatx4 __attribute__((ext_vector_type(4)));

// LDS row strides (in u32) chosen so every LDS access is at the 32-bank
// bandwidth floor (bank math in session journal):
//   As u32[16][SA]: b64 writes -> 4 dw/bank; b128 frag reads -> 8 dw/bank (floor)
//   Bs u32[32][SB]: b128 writes -> 8 dw/bank (floor); b32 frag reads -> 2/bank (floor)
#define SA 36
#define SB 68

__device__ __forceinline__ unsigned pack_bf16(float x, float y) {
    __hip_bfloat162 h = __float22bfloat162_rn(make_float2(x, y));  // v_cvt_pk_bf16_f32
    union { __hip_bfloat162 h; unsigned u; } v; v.h = h; return v.u;
}

__device__ __forceinline__ __half2 as_h2(unsigned u) {
    union { unsigned u; __half2 h; } v; v.u = u; return v.h;
}

// ---------------------------------------------------------------------------
// Kernel 1 (fused): M16 = half(x @ T) via bf16 MFMA, + copy x slice -> out,
// + init one o_b row to -1 (absorbs the self-similarity diagonal).
// Tile 16M x 64N, BK=64 (2 MFMA per wave per iter, 16 iters, 32 barriers).
// LDS layouts:
//   As u32[m][kp]   (kp = k/2 packed bf16 pair), stride SA=36
//   Bs u32[kp][n]   (pair-transposed),           stride SB=68
// Staging: A = 1 float4 -> 1 ds_write_b64; B = 4 float4 -> 2 ds_write_b128
// (conflict-free, vs previous 8-way-conflicted b32 writes).
// Grid (16 n, 32 m) = 512 blocks -> 2 blocks/CU, 8 waves/CU.
// ---------------------------------------------------------------------------
__global__ __launch_bounds__(256, 2) void gemm_fused(const float* __restrict__ A,
                                                     const float* __restrict__ B,
                                                     float* __restrict__ out,
                                                     __half* __restrict__ M16) {
    __shared__ unsigned As[16 * SA];
    __shared__ unsigned Bs[32 * SB];

    const int t    = threadIdx.x;
    const int lane = t & 63, w = t >> 6;
    const int bnx = blockIdx.x, bmy = blockIdx.y;
    const int bm = bmy * 16, bn = bnx * 64;

    // --- fused: copy x[bm..bm+16, bn..bn+64] -> out (16 rows x 64 cols) ---
    {
        const int r = t >> 4, c4 = (t & 15) * 4;
        *(float4*)&out[(size_t)(bm + r) * OROW + bn + c4] =
            *(const float4*)&A[(size_t)(bm + r) * INF + bn + c4];
    }
    // --- fused: out[row, 1024:1088] = -1 for row = linear block id (0..511) ---
    if (t < 16) {
        const int row = bmy * 16 + bnx;
        *(float4*)&out[(size_t)row * OROW + INF + t * 4] =
            make_float4(-1.f, -1.f, -1.f, -1.f);
    }

    // staging coords
    const int am  = t >> 4;            // A row 0..15
    const int ak  = (t & 15) * 4;      // A k-chunk (4 floats)
    const int bkp = t >> 4;            // B k-pair slot 0..15 (and +16)
    const int bn0 = (t & 15) * 4;      // B n-chunk (4 cols)

    // fragment pointers: A[m = lane&15][kp = q*4 + j], B[n = w*16 + lane&15][kp]
    const int q = lane >> 4, c = lane & 15;
    const unsigned* apo = &As[c * SA + q * 4];
    const unsigned* bpo = &Bs[(q * 4) * SB + w * 16 + c];

    floatx4 acc = {0.f, 0.f, 0.f, 0.f};

    const size_t aoff  = (size_t)(bm + am) * INF + ak;
    const float* Bbase = B + bn + bn0;

    // prefetch k0 = 0
    float4 av  = *(const float4*)&A[aoff];
    float4 b0a = *(const float4*)&Bbase[(size_t)(2 * bkp)      * PROJ];
    float4 b0b = *(const float4*)&Bbase[(size_t)(2 * bkp + 1)  * PROJ];
    float4 b1a = *(const float4*)&Bbase[(size_t)(2 * bkp + 32) * PROJ];
    float4 b1b = *(const float4*)&Bbase[(size_t)(2 * bkp + 33) * PROJ];

    for (int k0 = 0; k0 < INF; k0 += 64) {
        __syncthreads();   // previous iteration's frag reads complete
        *(uint2*)&As[am * SA + (ak >> 1)] =
            make_uint2(pack_bf16(av.x, av.y), pack_bf16(av.z, av.w));
        *(uint4*)&Bs[bkp * SB + bn0] =
            make_uint4(pack_bf16(b0a.x, b0b.x), pack_bf16(b0a.y, b0b.y),
                       pack_bf16(b0a.z, b0b.z), pack_bf16(b0a.w, b0b.w));
        *(uint4*)&Bs[(bkp + 16) * SB + bn0] =
            make_uint4(pack_bf16(b1a.x, b1b.x), pack_bf16(b1a.y, b1b.y),
                       pack_bf16(b1a.z, b1b.z), pack_bf16(b1a.w, b1b.w));
        __syncthreads();

        const int kn = k0 + 64;
        if (kn < INF) {    // issue next-iteration loads; in flight during MFMA
            av  = *(const float4*)&A[aoff + kn];
            b0a = *(const float4*)&Bbase[(size_t)(kn + 2 * bkp)      * PROJ];
            b0b = *(const float4*)&Bbase[(size_t)(kn + 2 * bkp + 1)  * PROJ];
            b1a = *(const float4*)&Bbase[(size_t)(kn + 2 * bkp + 32) * PROJ];
            b1b = *(const float4*)&Bbase[(size_t)(kn + 2 * bkp + 33) * PROJ];
        }

        union { uint4 u; short8 s; } alo, ahi;
        alo.u = *(const uint4*)(apo);        // kp 0..3   (k 0..31 of this tile)
        ahi.u = *(const uint4*)(apo + 16);   // kp 16..19 (k 32..63)
        union { unsigned u[4]; short8 s; } blo, bhi;
#pragma unroll
        for (int j = 0; j < 4; ++j) {
            blo.u[j] = bpo[j * SB];
            bhi.u[j] = bpo[(j + 16) * SB];
        }
        acc = __builtin_amdgcn_mfma_f32_16x16x32_bf16(alo.s, blo.s, acc, 0, 0, 0);
        acc = __builtin_amdgcn_mfma_f32_16x16x32_bf16(ahi.s, bhi.s, acc, 0, 0, 0);
    }

    // epilogue: C/D layout col=lane&15, row=(lane>>4)*4+r -> write fp16 M
#pragma unroll
    for (int r = 0; r < 4; ++r) {
        M16[(size_t)(bm + q * 4 + r) * PROJ + bn + w * 16 + c] = __float2half(acc[r]);
    }
}

// ---------------------------------------------------------------------------
// Kernel 2: pairwise L1 (packed fp16) + exp + sum over one 64-row j-slice.
// Register blocking: each thread owns TWO i-rows (i, i+32) -> each b128
// j-fragment read from LDS feeds two norms (halves LDS-read cost per op).
// Block = 128 thr (o 0..3 x il 0..31), tile 64 i x 64 j x 4 o.
// Grid (og 16, ig 8, js 8) = 1024 blocks -> 4 blocks/CU, 8 waves/CU.
// ---------------------------------------------------------------------------
__device__ __forceinline__ float l1norm16(const uint4 a0, const uint4 a1,
                                          const uint4 b0, const uint4 b1) {
    __half2 s0 = __hadd2(__habs2(__hsub2(as_h2(a0.x), as_h2(b0.x))),
                         __habs2(__hsub2(as_h2(a0.y), as_h2(b0.y))));
    __half2 s1 = __hadd2(__habs2(__hsub2(as_h2(a0.z), as_h2(b0.z))),
                         __habs2(__hsub2(as_h2(a0.w), as_h2(b0.w))));
    __half2 s2 = __hadd2(__habs2(__hsub2(as_h2(a1.x), as_h2(b1.x))),
                         __habs2(__hsub2(as_h2(a1.y), as_h2(b1.y))));
    __half2 s3 = __hadd2(__habs2(__hsub2(as_h2(a1.z), as_h2(b1.z))),
                         __habs2(__hsub2(as_h2(a1.w), as_h2(b1.w))));
    const __half2 s = __hadd2(__hadd2(s0, s1), __hadd2(s2, s3));
    return __low2float(s) + __high2float(s);
}

__global__ __launch_bounds__(128) void pairwise_h2(const __half* __restrict__ M16,
                                                   float* __restrict__ out) {
    __shared__ __half Mj[64 * 64];

    const int t  = threadIdx.x;
    const int o  = t & 3;
    const int il = t >> 2;               // 0..31
    const int og = blockIdx.x;           // 0..15
    const int ig = blockIdx.y;           // 0..7
    const int j0 = blockIdx.z * 64;      // 0..7 slices
    const int ia = ig * 64 + il;
    const int ib = ia + 32;

    // my two i-row fragments: 2 x 16 halves = 2 x 32 B
    const uint4* mpa = (const uint4*)&M16[(size_t)ia * PROJ + og * 64 + o * 16];
    const uint4* mpb = (const uint4*)&M16[(size_t)ib * PROJ + og * 64 + o * 16];
    const uint4 a0 = mpa[0], a1 = mpa[1];
    const uint4 a2 = mpb[0], a3 = mpb[1];

    // stage 64 j-rows x 64 halves (8 KB): 128 thr x 4 x 16 B
#pragma unroll
    for (int cc = 0; cc < 4; ++cc) {
        const int idx = (cc * 128 + t) * 8;  // half index
        const int jl  = idx >> 6;
        const int col = idx & 63;
        *(uint4*)&Mj[jl * 64 + col] =
            *(const uint4*)&M16[(size_t)(j0 + jl) * PROJ + og * 64 + col];
    }
    __syncthreads();

    float sa0 = 0.f, sa1 = 0.f, sb0 = 0.f, sb1 = 0.f;
#pragma unroll 4
    for (int jl = 0; jl < 64; ++jl) {
        const uint4 b0 = *(const uint4*)&Mj[jl * 64 + o * 16];
        const uint4 b1 = *(const uint4*)&Mj[jl * 64 + o * 16 + 8];
        const float na = l1norm16(a0, a1, b0, b1);
        const float nb = l1norm16(a2, a3, b0, b1);
        if (jl & 1) { sa1 += __expf(-na); sb1 += __expf(-nb); }
        else        { sa0 += __expf(-na); sb0 += __expf(-nb); }
    }

    __hip_atomic_fetch_add(&out[(size_t)ia * OROW + INF + og * 4 + o],
                           sa0 + sa1, __ATOMIC_RELAXED, __HIP_MEMORY_SCOPE_AGENT);
    __hip_atomic_fetch_add(&out[(size_t)ib * OROW + INF + og * 4 + o],
                           sb0 + sb1, __ATOMIC_RELAXED, __HIP_MEMORY_SCOPE_AGENT);
}

extern "C" void kernel_launch(void* const* d_in, const int* in_sizes, int n_in,
                              void* d_out, int out_size, void* d_ws, size_t ws_size,
                              hipStream_t stream) {
    const float* x = (const float*)d_in[0];   // [512,1024] fp32
    const float* T = (const float*)d_in[1];   // [1024,1024] fp32
    float* out  = (float*)d_out;              // [512,1088] fp32
    __half* M16 = (__half*)d_ws;              // [512,1024] fp16 scratch (1 MB)

    gemm_fused<<<dim3(PROJ / 64, NB / 16), 256, 0, stream>>>(x, T, out, M16);
    pairwise_h2<<<dim3(OUTF / 4, NB / 64, NB / 64), 128, 0, stream>>>(M16, out);
}

// Round 2
// 86.497 us; speedup vs baseline: 1.0700x; 1.0283x over previous
//
#include <hip/hip_runtime.h>
#include <hip/hip_bf16.h>
#include <hip/hip_fp16.h>

// Problem constants (fixed by reference)
#define NB     512
#define INF    1024
#define OUTF   64
#define PROJ   1024          // OUT_FEATURES * KERNEL_DIMS
#define OROW   (INF + OUTF)  // 1088

typedef short short8 __attribute__((ext_vector_type(8)));
typedef float floatx4 __attribute__((ext_vector_type(4)));

// LDS row strides in u32. Both multiples of 4 (b128 alignment). Bank math:
// every staging write and frag read lands at the 8-dw/bank floor.
#define SA 36   // As: 32 rows (m)  x 32 kp
#define SB 36   // Bs: 64 rows (n)  x 32 kp

__device__ __forceinline__ unsigned pack_bf16(float x, float y) {
    __hip_bfloat162 h = __float22bfloat162_rn(make_float2(x, y));  // v_cvt_pk_bf16_f32
    union { __hip_bfloat162 h; unsigned u; } v; v.h = h; return v.u;
}

__device__ __forceinline__ __half2 as_h2(unsigned u) {
    union { unsigned u; __half2 h; } v; v.u = u; return v.h;
}

// ---------------------------------------------------------------------------
// Kernel 1 (fused): M16 = half(x @ T) via bf16 MFMA, + copy x tile -> out,
// + init two o_b rows to -1 (absorbs the self-similarity diagonal).
// Tile 32M x 64N, BK=64, 512 thr (8 waves = 2 mt x 4 nq, one 16x16 each).
// BM=32 halves B's L2 traffic vs BM=16 (128 MB -> 64 MB, the old bottleneck).
// B is gathered per-k-row (coalesced 256 B per wave-load) and stored [n][kp]
// so both LDS writes (b128) and frag reads (b128) are conflict-free.
// Grid (16 n, 16 m) = 256 blocks -> 1 block/CU, 8 waves/CU.
// ---------------------------------------------------------------------------
__global__ __launch_bounds__(512, 1) void gemm_fused(const float* __restrict__ A,
                                                     const float* __restrict__ B,
                                                     float* __restrict__ out,
                                                     __half* __restrict__ M16) {
    __shared__ unsigned As[32 * SA];
    __shared__ unsigned Bs[64 * SB];

    const int t    = threadIdx.x;
    const int lane = t & 63, w = t >> 6;          // w = 0..7
    const int bnx = blockIdx.x, bmy = blockIdx.y;
    const int bm = bmy * 32, bn = bnx * 64;

    // --- fused: copy x[bm..bm+32, bn..bn+64] -> out ---
    {
        const int r = t >> 4, c4 = (t & 15) * 4;
        *(float4*)&out[(size_t)(bm + r) * OROW + bn + c4] =
            *(const float4*)&A[(size_t)(bm + r) * INF + bn + c4];
    }
    // --- fused: out[row, 1024:1088] = -1, two rows per block (0..511) ---
    if (t < 32) {
        const int row = (bmy * 16 + bnx) * 2 + (t >> 4);
        *(float4*)&out[(size_t)row * OROW + INF + (t & 15) * 4] =
            make_float4(-1.f, -1.f, -1.f, -1.f);
    }

    // staging coords
    const int am = t >> 3, ak = (t & 7) * 8;      // A: t<256 -> 32 rows x 64 k
    const int g  = w,      n0 = t & 63;           // B: 8 k-groups x 64 n

    // fragment coords: wave w -> (mt = w>>2, nq = w&3)
    const int q = lane >> 4, c = lane & 15;
    const int mt = w >> 2, nq = w & 3;
    const unsigned* ap = &As[(mt * 16 + c) * SA + q * 4];
    const unsigned* bp = &Bs[(nq * 16 + c) * SB + q * 4];

    floatx4 acc = {0.f, 0.f, 0.f, 0.f};

    const float* Acol = A + (size_t)(bm + am) * INF + ak;   // t<256 only
    const float* Bcol = B + bn + n0;

    // prefetch k0 = 0
    float4 av0, av1;
    if (t < 256) { av0 = *(const float4*)(Acol); av1 = *(const float4*)(Acol + 4); }
    float bv[8];
#pragma unroll
    for (int e = 0; e < 8; ++e) bv[e] = Bcol[(size_t)(g * 8 + e) * PROJ];

    for (int k0 = 0; k0 < INF; k0 += 64) {
        __syncthreads();   // previous iteration's frag reads complete
        if (t < 256) {
            *(uint4*)&As[am * SA + (ak >> 1)] =
                make_uint4(pack_bf16(av0.x, av0.y), pack_bf16(av0.z, av0.w),
                           pack_bf16(av1.x, av1.y), pack_bf16(av1.z, av1.w));
        }
        *(uint4*)&Bs[n0 * SB + g * 4] =
            make_uint4(pack_bf16(bv[0], bv[1]), pack_bf16(bv[2], bv[3]),
                       pack_bf16(bv[4], bv[5]), pack_bf16(bv[6], bv[7]));
        __syncthreads();

        const int kn = k0 + 64;
        if (kn < INF) {    // issue next-iteration loads; in flight during MFMA
            if (t < 256) {
                av0 = *(const float4*)(Acol + kn);
                av1 = *(const float4*)(Acol + kn + 4);
            }
#pragma unroll
            for (int e = 0; e < 8; ++e)
                bv[e] = Bcol[(size_t)(kn + g * 8 + e) * PROJ];
        }

        union { uint4 u; short8 s; } alo, ahi, blo, bhi;
        alo.u = *(const uint4*)(ap);        // k 0..31 of tile
        ahi.u = *(const uint4*)(ap + 16);   // k 32..63
        blo.u = *(const uint4*)(bp);
        bhi.u = *(const uint4*)(bp + 16);
        acc = __builtin_amdgcn_mfma_f32_16x16x32_bf16(alo.s, blo.s, acc, 0, 0, 0);
        acc = __builtin_amdgcn_mfma_f32_16x16x32_bf16(ahi.s, bhi.s, acc, 0, 0, 0);
    }

    // epilogue: C/D layout col=lane&15, row=(lane>>4)*4+r
#pragma unroll
    for (int r = 0; r < 4; ++r) {
        M16[(size_t)(bm + mt * 16 + q * 4 + r) * PROJ + bn + nq * 16 + c] =
            __float2half(acc[r]);
    }
}

// ---------------------------------------------------------------------------
// Kernel 2: pairwise L1 + exp, SYMMETRIC: each unordered 64-row tile pair
// {ti,tj} computed once. Row-sums (i side) per-thread; mirrored j-side sums
// recovered by a 4-step shfl_xor wave reduction over the 16 i-lanes and one
// atomic per (j,o). Diagonal pairs take the plain path (self term absorbed
// by the -1 init). Work drops ~1.5x vs the non-symmetric version (VALU-bound).
// Block 128 thr (o 0..3 x il 0..31); grid (36 pairs, 16 og, 2 jh) = 1152.
// ---------------------------------------------------------------------------
__device__ __forceinline__ float l1norm16(const uint4 a0, const uint4 a1,
                                          const uint4 b0, const uint4 b1) {
    __half2 s0 = __hadd2(__habs2(__hsub2(as_h2(a0.x), as_h2(b0.x))),
                         __habs2(__hsub2(as_h2(a0.y), as_h2(b0.y))));
    __half2 s1 = __hadd2(__habs2(__hsub2(as_h2(a0.z), as_h2(b0.z))),
                         __habs2(__hsub2(as_h2(a0.w), as_h2(b0.w))));
    __half2 s2 = __hadd2(__habs2(__hsub2(as_h2(a1.x), as_h2(b1.x))),
                         __habs2(__hsub2(as_h2(a1.y), as_h2(b1.y))));
    __half2 s3 = __hadd2(__habs2(__hsub2(as_h2(a1.z), as_h2(b1.z))),
                         __habs2(__hsub2(as_h2(a1.w), as_h2(b1.w))));
    const __half2 s = __hadd2(__hadd2(s0, s1), __hadd2(s2, s3));
    return __low2float(s) + __high2float(s);
}

__global__ __launch_bounds__(128) void pairwise_sym(const __half* __restrict__ M16,
                                                    float* __restrict__ out) {
    __shared__ __half Mj[32 * 64];    // j-tile slice (4 KB)
    __shared__ float jsum[32 * 8];    // [jl][o][w] mirrored partial sums

    const int t    = threadIdx.x;
    const int o    = t & 3;
    const int il   = t >> 2;              // 0..31
    const int w    = t >> 6;              // 0..1
    const int og   = blockIdx.y;          // 0..15
    const int jh   = blockIdx.z;          // 0..1

    // decode unordered pair index 0..35 -> (ti, tj), ti <= tj, tiles of 64
    int ti = 0, rem = blockIdx.x;
    while (rem >= 8 - ti) { rem -= 8 - ti; ++ti; }
    const int tj = ti + rem;
    const bool diag = (ti == tj);

    const int j0 = tj * 64 + jh * 32;
    const int ia = ti * 64 + il;
    const int ib = ia + 32;

    // my two i-row fragments
    const uint4* mpa = (const uint4*)&M16[(size_t)ia * PROJ + og * 64 + o * 16];
    const uint4* mpb = (const uint4*)&M16[(size_t)ib * PROJ + og * 64 + o * 16];
    const uint4 a0 = mpa[0], a1 = mpa[1];
    const uint4 a2 = mpb[0], a3 = mpb[1];

    // stage 32 j-rows x 64 halves (4 KB): 128 thr x 2 x 16 B
#pragma unroll
    for (int cc = 0; cc < 2; ++cc) {
        const int idx = (cc * 128 + t) * 8;  // half index
        const int jl  = idx >> 6;
        const int col = idx & 63;
        *(uint4*)&Mj[jl * 64 + col] =
            *(const uint4*)&M16[(size_t)(j0 + jl) * PROJ + og * 64 + col];
    }
    __syncthreads();

    float sa0 = 0.f, sa1 = 0.f, sb0 = 0.f, sb1 = 0.f;
#pragma unroll 4
    for (int jl = 0; jl < 32; ++jl) {
        const uint4 b0 = *(const uint4*)&Mj[jl * 64 + o * 16];
        const uint4 b1 = *(const uint4*)&Mj[jl * 64 + o * 16 + 8];
        const float na = l1norm16(a0, a1, b0, b1);
        const float nb = l1norm16(a2, a3, b0, b1);
        const float ea = __expf(-na);
        const float eb = __expf(-nb);
        if (jl & 1) { sa1 += ea; sb1 += eb; }
        else        { sa0 += ea; sb0 += eb; }
        if (!diag) {
            // mirrored contribution: sum over this wave's 16 i-lanes
            float jc = ea + eb;
            jc += __shfl_xor(jc, 4);
            jc += __shfl_xor(jc, 8);
            jc += __shfl_xor(jc, 16);
            jc += __shfl_xor(jc, 32);
            jsum[jl * 8 + o * 2 + w] = jc;   // 16 lanes, same addr, same value
        }
    }

    __hip_atomic_fetch_add(&out[(size_t)ia * OROW + INF + og * 4 + o],
                           sa0 + sa1, __ATOMIC_RELAXED, __HIP_MEMORY_SCOPE_AGENT);
    __hip_atomic_fetch_add(&out[(size_t)ib * OROW + INF + og * 4 + o],
                           sb0 + sb1, __ATOMIC_RELAXED, __HIP_MEMORY_SCOPE_AGENT);

    if (!diag) {
        __syncthreads();
        const float v = jsum[2 * t] + jsum[2 * t + 1];   // combine both waves
        __hip_atomic_fetch_add(&out[(size_t)(j0 + (t >> 2)) * OROW + INF + og * 4 + (t & 3)],
                               v, __ATOMIC_RELAXED, __HIP_MEMORY_SCOPE_AGENT);
    }
}

extern "C" void kernel_launch(void* const* d_in, const int* in_sizes, int n_in,
                              void* d_out, int out_size, void* d_ws, size_t ws_size,
                              hipStream_t stream) {
    const float* x = (const float*)d_in[0];   // [512,1024] fp32
    const float* T = (const float*)d_in[1];   // [1024,1024] fp32
    float* out  = (float*)d_out;              // [512,1088] fp32
    __half* M16 = (__half*)d_ws;              // [512,1024] fp16 scratch (1 MB)

    gemm_fused<<<dim3(PROJ / 64, NB / 32), 512, 0, stream>>>(x, T, out, M16);
    pairwise_sym<<<dim3(36, 16, 2), 128, 0, stream>>>(M16, out);
}